// Round 18
// baseline (1087.003 us; speedup 1.0000x reference)
//
#include <hip/hip_runtime.h>
#include <hip/hip_bf16.h>
#include <stdint.h>

#define E_ 4
#define T_ 4096
#define D_ 2048
#define H_ 8192

typedef __attribute__((ext_vector_type(8))) short bf16x8;
typedef __attribute__((ext_vector_type(4))) float f32x4;
typedef __attribute__((ext_vector_type(4))) unsigned short u16x4;

__device__ __forceinline__ unsigned short f2bf(float f) {
    unsigned int u = __float_as_uint(f);
    u = u + 0x7fffu + ((u >> 16) & 1u);
    return (unsigned short)(u >> 16);
}

// async global->LDS, 16B per lane. LDS dest is wave-uniform base; HW adds lane*16.
__device__ __forceinline__ void async16(const unsigned short* g, unsigned short* l) {
    auto gp = (const __attribute__((address_space(1))) unsigned int*)g;
    auto lp = (__attribute__((address_space(3))) unsigned int*)l;
    __builtin_amdgcn_global_load_lds(gp, lp, 16, 0, 0);
}

__device__ __forceinline__ f32x4 mfma16(bf16x8 a, bf16x8 b, f32x4 c) {
    return __builtin_amdgcn_mfma_f32_16x16x32_bf16(a, b, c, 0, 0, 0);
}

// ---------------- x: f32 -> bf16 ----------------
__global__ void cvt_x_kernel(const float4* __restrict__ in, uint2* __restrict__ out, long n4) {
    long i = (long)blockIdx.x * blockDim.x + threadIdx.x;
    long stride = (long)gridDim.x * blockDim.x;
    for (; i < n4; i += stride) {
        float4 v = in[i];
        uint2 o;
        o.x = (unsigned)f2bf(v.x) | ((unsigned)f2bf(v.y) << 16);
        o.y = (unsigned)f2bf(v.z) | ((unsigned)f2bf(v.w) << 16);
        out[i] = o;
    }
}

// ---------------- W (R x C, f32) -> Wt (C x R, bf16) per expert ----------------
__global__ void transpose_cvt_kernel(const float* __restrict__ W, unsigned short* __restrict__ Wt,
                                     int R, int C) {
    __shared__ float tile[64][65];
    const float* Wp = W + (size_t)blockIdx.z * R * C;
    unsigned short* Wtp = Wt + (size_t)blockIdx.z * R * C;
    const int c0 = blockIdx.x * 64, r0 = blockIdx.y * 64;
    const int tc = threadIdx.x & 63;
    const int tr = threadIdx.x >> 6;
#pragma unroll
    for (int i = 0; i < 16; ++i) {
        int r = tr * 16 + i;
        tile[r][tc] = Wp[(size_t)(r0 + r) * C + c0 + tc];
    }
    __syncthreads();
#pragma unroll
    for (int i = 0; i < 16; ++i) {
        int r = tr * 16 + i;
        Wtp[(size_t)(c0 + r) * R + r0 + tc] = f2bf(tile[tc][r]);
    }
}

// ------ 256x256 8-phase GEMM: balanced 6/6/6/6 reads, MFMA-bound every phase ------
// r18 change vs r17: per-phase LDS-port time (was {4,8,0,12} reads/wave = up to 1152cy/CU
// vs 621cy MFMA shadow) rebalanced to 6/6/6/6 (576cy < 621cy -> MFMA-bound each phase).
//  * dedicated ah[4][2] regs for a-hi so its reads start at P1 (no WAR vs a-lo in use)
//  * vmcnt moved P4->P3 (P8->P7), count 4. Ledger (per wave, call units): entering P1
//    in-flight 6 {a-lo(tB),B(tB)h0,B(tB)h1}; P1 +a-hi(tB)=8; P2 +a-lo(tA+2)=10;
//    P3 +B(tA+2)h0=12, vmcnt(4) completes 8 oldest = TILE tB ENTIRELY; P4 +B(tA+2)h1=6;
//    P5..P8 mirror -> P7's vmcnt(4) completes tile tA+2. Invariant restored.
// Read placement (consumer >= 1 barrier later; WAR audited):
//   P1: Q(0,0){a,b01}; post: b23(tA) 4 + ah frag0 2
//   P2: Q(0,2){a,b23}; post: ah frags1-3 6
//   P3: Q(4,0){ah,b01}; [vmcnt] post: b01(tB) 4 (b01 free) + a frag0 2 (a free)
//   P4: Q(4,2){ah,b23}; post: a frags1-3 6        (P5-P8 mirror on slot 1)
// Stage cadence (r14-validated): P1 a-hi(tB); P2 a-lo(tA+2); P3 B(tA+2)h0; P4 B(tA+2)h1;
//   P5 a-hi(tA+2); P6 a-lo(tB+2); P7 B(tB+2)h0; P8 B(tB+2)h1.
// Tail: stages+next-tile reads guarded; vmcnt(0) @P3/P7.
template <int K, int OUT_MODE>
__global__ __launch_bounds__(512, 2) void gemm256_kernel(
    const unsigned short* __restrict__ A,   // [E][M][K]
    const unsigned short* __restrict__ Bt,  // [E][N][K]
    const float* __restrict__ bias,         // [E][N]
    void* __restrict__ Cout,                // [E][M][N]
    int M, int N)
{
    constexpr int BK = 64;
    constexpr int NT = K / BK;              // even (32 / 128)
    __shared__ __align__(16) unsigned short L[2][2][2][128][64];

    // ---- XCD chunk + L3 supertile remap (r5-validated) ----
    const int nx = gridDim.x, ny = gridDim.y;
    const int nwg = nx * ny * gridDim.z;
    const int w = (blockIdx.z * ny + blockIdx.y) * nx + blockIdx.x;
    const int cpx = nwg >> 3;
    const int xcd = w & 7;
    const int c = w >> 3;
    const int CR = cpx / nx;
    const int GX = (nx % 16 == 0) ? 16 : nx;
    const int g = c / (GX * CR);
    const int r1 = c - g * (GX * CR);
    const int byl = r1 / GX;
    const int bxi = r1 - byl * GX;
    const int fy = xcd * CR + byl;
    const int bx = g * GX + bxi;
    const int e = fy / ny;
    const int by = fy - e * ny;

    const unsigned short* Ae = A + (size_t)e * M * K;
    const unsigned short* Be = Bt + (size_t)e * N * K;
    const int bm0 = by * 256;
    const int bn0 = bx * 256;

    const int tid = threadIdx.x;
    const int lane = tid & 63;
    const int wid = tid >> 6;
    const int wr = wid >> 2;
    const int wc = wid & 3;

    // ---- staging geometry: one async16 call = one 64-row region slice (8 rows/wave)
    const int srow8 = wid * 8 + (lane >> 3);
    const int skel = 8 * ((lane & 7) ^ (lane >> 3));
    const unsigned short* Abase = Ae + (size_t)(bm0 + srow8) * K + skel;
    const unsigned short* Bbase = Be + (size_t)(bn0 + srow8) * K + skel;

#define STG_A(S_, T_, H_, RO_) \
    async16(Abase + ((size_t)((H_) * 128 + (RO_)) * K + (T_) * BK), \
            &L[S_][0][H_][(RO_) + wid * 8][0])
#define STG_B(S_, T_, H_, RO_) \
    async16(Bbase + ((size_t)((H_) * 128 + (RO_)) * K + (T_) * BK), \
            &L[S_][1][H_][(RO_) + wid * 8][0])

    // ---- fragment-read geometry (r5-verified swizzle) ----
    const int fr = lane & 15;
    const int kq = lane >> 4;
    const int ksw = (lane & 7) << 3;
    const int bh = wc >> 1;
    const int brb = (wc & 1) * 64;

#define RD_AF(S_, ARR_, MOFF_, M0_, M1_) \
    _Pragma("unroll") for (int m = (M0_); m < (M1_); ++m) \
    _Pragma("unroll") for (int kk = 0; kk < 2; ++kk) \
        ARR_[m][kk] = *(const bf16x8*)&L[S_][0][wr][(m + (MOFF_)) * 16 + fr][(kk * 32 + kq * 8) ^ ksw]
#define RD_B(S_, N0_, N1_) \
    _Pragma("unroll") for (int n = (N0_); n < (N1_); ++n) \
    _Pragma("unroll") for (int kk = 0; kk < 2; ++kk) \
        b[n][kk] = *(const bf16x8*)&L[S_][1][bh][brb + n * 16 + fr][(kk * 32 + kq * 8) ^ ksw]

#define CLOSEBAR do { __builtin_amdgcn_s_barrier(); __builtin_amdgcn_sched_barrier(0); } while (0)
#define MFMA_Q(ARR_, MB_, NB_) do { __builtin_amdgcn_s_setprio(1); \
    _Pragma("unroll") for (int m = 0; m < 4; ++m) \
    _Pragma("unroll") for (int n = 0; n < 2; ++n) \
    _Pragma("unroll") for (int kk = 0; kk < 2; ++kk) \
        acc[(MB_) + m][(NB_) + n] = mfma16(ARR_[m][kk], b[(NB_) + n][kk], acc[(MB_) + m][(NB_) + n]); \
    __builtin_amdgcn_s_setprio(0); } while (0)

    f32x4 acc[8][4] = {};
    bf16x8 a[4][2], ah[4][2], b[4][2];

    // ---- prologue: tile0 full (8 calls) + tile1 minus a-hi (6 calls)
    STG_A(0, 0, 0, 0);  STG_A(0, 0, 1, 0);   // a-lo(0)
    STG_B(0, 0, 0, 0);  STG_B(0, 0, 0, 64);  // B(0) h0
    STG_B(0, 0, 1, 0);  STG_B(0, 0, 1, 64);  // B(0) h1
    STG_A(0, 0, 0, 64); STG_A(0, 0, 1, 64);  // a-hi(0)
    STG_A(1, 1, 0, 0);  STG_A(1, 1, 1, 0);   // a-lo(1)
    STG_B(1, 1, 0, 0);  STG_B(1, 1, 0, 64);  // B(1) h0
    STG_B(1, 1, 1, 0);  STG_B(1, 1, 1, 64);  // B(1) h1
    asm volatile("s_waitcnt vmcnt(6)" ::: "memory"); // tile0 (oldest 8) landed
    __builtin_amdgcn_sched_barrier(0);
    __builtin_amdgcn_s_barrier();
    RD_B(0, 0, 2);                                   // preload b01(tile0)
    RD_AF(0, a, 0, 0, 4);                            // preload a-lo(tile0)

#define ITER(NOTLAST_) do { \
        const int tA = 2 * j, tB = tA + 1; \
        /* P1: Q(0,0); post: b23(tA) + ah frag0 */ \
        STG_A(1, tB, 0, 64); STG_A(1, tB, 1, 64); \
        __builtin_amdgcn_sched_barrier(0); \
        MFMA_Q(a, 0, 0); \
        RD_B(0, 2, 4); \
        RD_AF(0, ah, 4, 0, 1); \
        CLOSEBAR; \
        /* P2: Q(0,2); post: ah frags1-3 */ \
        if (NOTLAST_) { STG_A(0, tA + 2, 0, 0); STG_A(0, tA + 2, 1, 0); } \
        __builtin_amdgcn_sched_barrier(0); \
        MFMA_Q(a, 0, 2); \
        RD_AF(0, ah, 4, 1, 4); \
        CLOSEBAR; \
        /* P3: Q(4,0); vmcnt certifies tile tB; post: b01(tB) + a frag0(tB) */ \
        if (NOTLAST_) { STG_B(0, tA + 2, 0, 0); STG_B(0, tA + 2, 0, 64); } \
        if (NOTLAST_) { asm volatile("s_waitcnt vmcnt(4)" ::: "memory"); } \
        else         { asm volatile("s_waitcnt vmcnt(0)" ::: "memory"); } \
        __builtin_amdgcn_sched_barrier(0); \
        MFMA_Q(ah, 4, 0); \
        RD_B(1, 0, 2); \
        RD_AF(1, a, 0, 0, 1); \
        CLOSEBAR; \
        /* P4: Q(4,2); post: a frags1-3(tB) */ \
        if (NOTLAST_) { STG_B(0, tA + 2, 1, 0); STG_B(0, tA + 2, 1, 64); } \
        __builtin_amdgcn_sched_barrier(0); \
        MFMA_Q(ah, 4, 2); \
        RD_AF(1, a, 0, 1, 4); \
        CLOSEBAR; \
        /* P5: Q(0,0) on tB; post: b23(tB) + ah frag0(tB) */ \
        if (NOTLAST_) { STG_A(0, tA + 2, 0, 64); STG_A(0, tA + 2, 1, 64); } \
        __builtin_amdgcn_sched_barrier(0); \
        MFMA_Q(a, 0, 0); \
        RD_B(1, 2, 4); \
        RD_AF(1, ah, 4, 0, 1); \
        CLOSEBAR; \
        /* P6: Q(0,2); post: ah frags1-3(tB) */ \
        if (NOTLAST_) { STG_A(1, tB + 2, 0, 0); STG_A(1, tB + 2, 1, 0); } \
        __builtin_amdgcn_sched_barrier(0); \
        MFMA_Q(a, 0, 2); \
        RD_AF(1, ah, 4, 1, 4); \
        CLOSEBAR; \
        /* P7: Q(4,0); vmcnt certifies tile tA+2; post (guarded): b01+a frag0(tA+2) */ \
        if (NOTLAST_) { STG_B(1, tB + 2, 0, 0); STG_B(1, tB + 2, 0, 64); } \
        if (NOTLAST_) { asm volatile("s_waitcnt vmcnt(4)" ::: "memory"); } \
        else         { asm volatile("s_waitcnt vmcnt(0)" ::: "memory"); } \
        __builtin_amdgcn_sched_barrier(0); \
        MFMA_Q(ah, 4, 0); \
        if (NOTLAST_) { RD_B(0, 0, 2); RD_AF(0, a, 0, 0, 1); } \
        CLOSEBAR; \
        /* P8: Q(4,2); post (guarded): a frags1-3(tA+2) */ \
        if (NOTLAST_) { STG_B(1, tB + 2, 1, 0); STG_B(1, tB + 2, 1, 64); } \
        __builtin_amdgcn_sched_barrier(0); \
        MFMA_Q(ah, 4, 2); \
        if (NOTLAST_) { RD_AF(0, a, 0, 1, 4); } \
        CLOSEBAR; \
    } while (0)

    for (int j = 0; j < NT / 2 - 1; ++j) { ITER(true); }
    { const int j = NT / 2 - 1; ITER(false); }

#undef ITER
#undef MFMA_Q
#undef CLOSEBAR
#undef RD_AF
#undef RD_B
#undef STG_A
#undef STG_B

    // ---- epilogue: LDS-transpose to contiguous row stores (r5-validated) ----
    constexpr int ST = 260;
    float* S = (float*)&L[0][0][0][0][0];
    const int rowq = (lane >> 4) * 4;
    const float* bp = bias + (size_t)e * N;
    const float4 bb4 = *(const float4*)(bp + bn0 + lane * 4);

    unsigned short* Y = (unsigned short*)Cout + (size_t)e * M * N;
    float* O = (float*)Cout + (size_t)e * M * N;

#pragma unroll
    for (int sg = 0; sg < 8; ++sg) {
        __syncthreads();
        if (wr == (sg >> 2)) {
            const int sl = sg & 3;
#pragma unroll
            for (int mm = 0; mm < 2; ++mm) {
#pragma unroll
                for (int n = 0; n < 4; ++n) {
#pragma unroll
                    for (int j2 = 0; j2 < 4; ++j2) {
                        S[(mm * 16 + rowq + j2) * ST + wc * 64 + n * 16 + fr] =
                            acc[2 * sl + mm][n][j2];
                    }
                }
            }
        }
        __syncthreads();
#pragma unroll
        for (int rr = 0; rr < 4; ++rr) {
            const int rl = wid * 4 + rr;
            const int rg = bm0 + sg * 32 + rl;
            f32x4 v = *(const f32x4*)&S[rl * ST + lane * 4];
            v[0] += bb4.x; v[1] += bb4.y; v[2] += bb4.z; v[3] += bb4.w;
            if (OUT_MODE == 0) {
                u16x4 o;
                o[0] = f2bf(fmaxf(v[0], 0.0f));
                o[1] = f2bf(fmaxf(v[1], 0.0f));
                o[2] = f2bf(fmaxf(v[2], 0.0f));
                o[3] = f2bf(fmaxf(v[3], 0.0f));
                *(u16x4*)(Y + (size_t)rg * N + bn0 + lane * 4) = o;
            } else {
                *(f32x4*)(O + (size_t)rg * N + bn0 + lane * 4) = v;
            }
        }
    }
}

extern "C" void kernel_launch(void* const* d_in, const int* in_sizes, int n_in,
                              void* d_out, int out_size, void* d_ws, size_t ws_size,
                              hipStream_t stream) {
    const float* x     = (const float*)d_in[0]; // (E,T,D)
    const float* fc1_w = (const float*)d_in[1]; // (E,D,H)
    const float* fc1_b = (const float*)d_in[2]; // (E,1,H)
    const float* fc2_w = (const float*)d_in[3]; // (E,H,D)
    const float* fc2_b = (const float*)d_in[4]; // (E,1,D)
    float* out = (float*)d_out;

    const size_t n_x  = (size_t)E_ * T_ * D_;
    const size_t n_w1 = (size_t)E_ * D_ * H_;
    const size_t n_w2 = (size_t)E_ * H_ * D_;
    const size_t n_y1 = (size_t)E_ * T_ * H_;

    const size_t need = (n_x + n_w1 + n_w2 + n_y1) * sizeof(unsigned short);
    if (ws_size < need) return;

    unsigned short* xb  = (unsigned short*)d_ws;
    unsigned short* w1t = xb + n_x;    // (E,H,D)
    unsigned short* w2t = w1t + n_w1;  // (E,D,H)
    unsigned short* y1  = w2t + n_w2;  // (E,T,H)

    cvt_x_kernel<<<2048, 256, 0, stream>>>((const float4*)x, (uint2*)xb, (long)(n_x / 4));
    {
        dim3 g(H_ / 64, D_ / 64, E_);
        transpose_cvt_kernel<<<g, 256, 0, stream>>>(fc1_w, w1t, D_, H_);
    }
    {
        dim3 g(D_ / 64, H_ / 64, E_);
        transpose_cvt_kernel<<<g, 256, 0, stream>>>(fc2_w, w2t, H_, D_);
    }
    // GEMM1: y1 = relu(x @ W1 + b1), bf16 out. M=T, N=H, K=D
    {
        dim3 g(H_ / 256, T_ / 256, E_);
        gemm256_kernel<D_, 0><<<g, 512, 0, stream>>>(xb, w1t, fc1_b, (void*)y1, T_, H_);
    }
    // GEMM2: out = y1 @ W2 + b2, f32 out. M=T, N=D, K=H
    {
        dim3 g(D_ / 256, T_ / 256, E_);
        gemm256_kernel<H_, 1><<<g, 512, 0, stream>>>(y1, w2t, fc2_b, (void*)out, T_, D_);
    }
}

// Round 21
// 1069.265 us; speedup vs baseline: 1.0166x; 1.0166x over previous
//
#include <hip/hip_runtime.h>
#include <hip/hip_bf16.h>
#include <stdint.h>

#define E_ 4
#define T_ 4096
#define D_ 2048
#define H_ 8192

typedef __attribute__((ext_vector_type(8))) short bf16x8;
typedef __attribute__((ext_vector_type(4))) float f32x4;
typedef __attribute__((ext_vector_type(4))) unsigned short u16x4;

__device__ __forceinline__ unsigned short f2bf(float f) {
    unsigned int u = __float_as_uint(f);
    u = u + 0x7fffu + ((u >> 16) & 1u);
    return (unsigned short)(u >> 16);
}

// async global->LDS, 16B per lane. LDS dest is wave-uniform base; HW adds lane*16.
__device__ __forceinline__ void async16(const unsigned short* g, unsigned short* l) {
    auto gp = (const __attribute__((address_space(1))) unsigned int*)g;
    auto lp = (__attribute__((address_space(3))) unsigned int*)l;
    __builtin_amdgcn_global_load_lds(gp, lp, 16, 0, 0);
}

__device__ __forceinline__ f32x4 mfma16(bf16x8 a, bf16x8 b, f32x4 c) {
    return __builtin_amdgcn_mfma_f32_16x16x32_bf16(a, b, c, 0, 0, 0);
}

// ---------------- x: f32 -> bf16 ----------------
__global__ void cvt_x_kernel(const float4* __restrict__ in, uint2* __restrict__ out, long n4) {
    long i = (long)blockIdx.x * blockDim.x + threadIdx.x;
    long stride = (long)gridDim.x * blockDim.x;
    for (; i < n4; i += stride) {
        float4 v = in[i];
        uint2 o;
        o.x = (unsigned)f2bf(v.x) | ((unsigned)f2bf(v.y) << 16);
        o.y = (unsigned)f2bf(v.z) | ((unsigned)f2bf(v.w) << 16);
        out[i] = o;
    }
}

// ---------------- W (R x C, f32) -> Wt (C x R, bf16) per expert ----------------
__global__ void transpose_cvt_kernel(const float* __restrict__ W, unsigned short* __restrict__ Wt,
                                     int R, int C) {
    __shared__ float tile[64][65];
    const float* Wp = W + (size_t)blockIdx.z * R * C;
    unsigned short* Wtp = Wt + (size_t)blockIdx.z * R * C;
    const int c0 = blockIdx.x * 64, r0 = blockIdx.y * 64;
    const int tc = threadIdx.x & 63;
    const int tr = threadIdx.x >> 6;
#pragma unroll
    for (int i = 0; i < 16; ++i) {
        int r = tr * 16 + i;
        tile[r][tc] = Wp[(size_t)(r0 + r) * C + c0 + tc];
    }
    __syncthreads();
#pragma unroll
    for (int i = 0; i < 16; ++i) {
        int r = tr * 16 + i;
        Wtp[(size_t)(c0 + r) * R + r0 + tc] = f2bf(tile[tc][r]);
    }
}

// -------- 256x256 8-phase GEMM: 1-barrier phases, fully one-phase-ahead reads --------
// r21 = EXACT revert to the r17 kernel (best measured passing: 1074.65us, MfmaUtil 54-55%).
// r19/r20 bisection proved the global_load_lds offset-immediate path corrupts data on
// gfx950 — all staging displacement must be baked into the per-lane address (as here).
// Read placement per half-tile (phases P1-P4, tile tA slot0):
//   P4-prev: [vmcnt] RD b01(tA); Q(4,2)prev; RD a-lo(tA)      <- both certified by vmcnt
//   P1: Q(0,0); post: RD b23(tA)
//   P2: Q(0,2); post: RD a-hi(tA)
//   P3: Q(4,0)
//   P4: [vmcnt] RD b01(tB); Q(4,2); RD a-lo(tB)
// Stage cadence (r14-validated): P1 a-hi(tB); P2 a-lo(tA+2); P3 B(tA+2)h0;
//   P4 B(tA+2)h1+vm6; P5 a-hi(tA+2); P6 a-lo(tB+2); P7 B(tB+2)h0; P8 B(tB+2)h1+vm6.
// Tail: P4's reads unconditional (tB = last tile); P8's guarded; vmcnt(0) @P4/P8 last iter.
template <int K, int OUT_MODE>
__global__ __launch_bounds__(512, 2) void gemm256_kernel(
    const unsigned short* __restrict__ A,   // [E][M][K]
    const unsigned short* __restrict__ Bt,  // [E][N][K]
    const float* __restrict__ bias,         // [E][N]
    void* __restrict__ Cout,                // [E][M][N]
    int M, int N)
{
    constexpr int BK = 64;
    constexpr int NT = K / BK;              // even (32 / 128)
    __shared__ __align__(16) unsigned short L[2][2][2][128][64];

    // ---- XCD chunk + L3 supertile remap (r5-validated) ----
    const int nx = gridDim.x, ny = gridDim.y;
    const int nwg = nx * ny * gridDim.z;
    const int w = (blockIdx.z * ny + blockIdx.y) * nx + blockIdx.x;
    const int cpx = nwg >> 3;
    const int xcd = w & 7;
    const int c = w >> 3;
    const int CR = cpx / nx;
    const int GX = (nx % 16 == 0) ? 16 : nx;
    const int g = c / (GX * CR);
    const int r1 = c - g * (GX * CR);
    const int byl = r1 / GX;
    const int bxi = r1 - byl * GX;
    const int fy = xcd * CR + byl;
    const int bx = g * GX + bxi;
    const int e = fy / ny;
    const int by = fy - e * ny;

    const unsigned short* Ae = A + (size_t)e * M * K;
    const unsigned short* Be = Bt + (size_t)e * N * K;
    const int bm0 = by * 256;
    const int bn0 = bx * 256;

    const int tid = threadIdx.x;
    const int lane = tid & 63;
    const int wid = tid >> 6;
    const int wr = wid >> 2;
    const int wc = wid & 3;

    // ---- staging geometry: one async16 call = one 64-row region slice (8 rows/wave)
    const int srow8 = wid * 8 + (lane >> 3);
    const int skel = 8 * ((lane & 7) ^ (lane >> 3));
    const unsigned short* Abase = Ae + (size_t)(bm0 + srow8) * K + skel;
    const unsigned short* Bbase = Be + (size_t)(bn0 + srow8) * K + skel;

#define STG_A(S_, T_, H_, RO_) \
    async16(Abase + ((size_t)((H_) * 128 + (RO_)) * K + (T_) * BK), \
            &L[S_][0][H_][(RO_) + wid * 8][0])
#define STG_B(S_, T_, H_, RO_) \
    async16(Bbase + ((size_t)((H_) * 128 + (RO_)) * K + (T_) * BK), \
            &L[S_][1][H_][(RO_) + wid * 8][0])

    // ---- fragment-read geometry (r5-verified swizzle) ----
    const int fr = lane & 15;
    const int kq = lane >> 4;
    const int ksw = (lane & 7) << 3;
    const int bh = wc >> 1;
    const int brb = (wc & 1) * 64;

#define RD_A(S_, MOFF_) \
    _Pragma("unroll") for (int m = 0; m < 4; ++m) \
    _Pragma("unroll") for (int kk = 0; kk < 2; ++kk) \
        a[m][kk] = *(const bf16x8*)&L[S_][0][wr][(m + (MOFF_)) * 16 + fr][(kk * 32 + kq * 8) ^ ksw]
#define RD_B(S_, N0_, N1_) \
    _Pragma("unroll") for (int n = (N0_); n < (N1_); ++n) \
    _Pragma("unroll") for (int kk = 0; kk < 2; ++kk) \
        b[n][kk] = *(const bf16x8*)&L[S_][1][bh][brb + n * 16 + fr][(kk * 32 + kq * 8) ^ ksw]

#define CLOSEBAR do { __builtin_amdgcn_s_barrier(); __builtin_amdgcn_sched_barrier(0); } while (0)
#define MFMA_Q(MB_, NB_) do { __builtin_amdgcn_s_setprio(1); \
    _Pragma("unroll") for (int m = 0; m < 4; ++m) \
    _Pragma("unroll") for (int n = 0; n < 2; ++n) \
    _Pragma("unroll") for (int kk = 0; kk < 2; ++kk) \
        acc[(MB_) + m][(NB_) + n] = mfma16(a[m][kk], b[(NB_) + n][kk], acc[(MB_) + m][(NB_) + n]); \
    __builtin_amdgcn_s_setprio(0); } while (0)

    f32x4 acc[8][4] = {};
    bf16x8 a[4][2], b[4][2];

    // ---- prologue: tile0 full (8 calls) + tile1 minus a-hi (6 calls); a-hi(1) comes at P1
    STG_A(0, 0, 0, 0);  STG_A(0, 0, 1, 0);   // a-lo(0)
    STG_B(0, 0, 0, 0);  STG_B(0, 0, 0, 64);  // B(0) h0
    STG_B(0, 0, 1, 0);  STG_B(0, 0, 1, 64);  // B(0) h1
    STG_A(0, 0, 0, 64); STG_A(0, 0, 1, 64);  // a-hi(0)
    STG_A(1, 1, 0, 0);  STG_A(1, 1, 1, 0);   // a-lo(1)
    STG_B(1, 1, 0, 0);  STG_B(1, 1, 0, 64);  // B(1) h0
    STG_B(1, 1, 1, 0);  STG_B(1, 1, 1, 64);  // B(1) h1
    asm volatile("s_waitcnt vmcnt(6)" ::: "memory"); // tile0 (oldest 8) landed
    __builtin_amdgcn_sched_barrier(0);
    __builtin_amdgcn_s_barrier();
    RD_B(0, 0, 2);                                   // preload b01(tile0)
    RD_A(0, 0);                                      // preload a-lo(tile0)

#define ITER(NOTLAST_) do { \
        const int tA = 2 * j, tB = tA + 1; \
        /* P1: Q(0,0) [deps: P4-prev reads]; post: b23(tA) */ \
        STG_A(1, tB, 0, 64); STG_A(1, tB, 1, 64); \
        __builtin_amdgcn_sched_barrier(0); \
        MFMA_Q(0, 0); \
        RD_B(0, 2, 4); \
        CLOSEBAR; \
        /* P2: Q(0,2); post: a-hi(tA) */ \
        if (NOTLAST_) { STG_A(0, tA + 2, 0, 0); STG_A(0, tA + 2, 1, 0); } \
        __builtin_amdgcn_sched_barrier(0); \
        MFMA_Q(0, 2); \
        RD_A(0, 4); \
        CLOSEBAR; \
        /* P3: Q(4,0) */ \
        if (NOTLAST_) { STG_B(0, tA + 2, 0, 0); STG_B(0, tA + 2, 0, 64); } \
        __builtin_amdgcn_sched_barrier(0); \
        MFMA_Q(4, 0); \
        CLOSEBAR; \
        /* P4: vmcnt certifies tile tB; b01(tB); Q(4,2); a-lo(tB) [WAR after cluster] */ \
        if (NOTLAST_) { STG_B(0, tA + 2, 1, 0); STG_B(0, tA + 2, 1, 64); } \
        if (NOTLAST_) { asm volatile("s_waitcnt vmcnt(6)" ::: "memory"); } \
        else         { asm volatile("s_waitcnt vmcnt(0)" ::: "memory"); } \
        __builtin_amdgcn_sched_barrier(0); \
        RD_B(1, 0, 2); \
        MFMA_Q(4, 2); \
        RD_A(1, 0); \
        CLOSEBAR; \
        /* P5: Q(0,0) on tB; post: b23(tB) */ \
        if (NOTLAST_) { STG_A(0, tA + 2, 0, 64); STG_A(0, tA + 2, 1, 64); } \
        __builtin_amdgcn_sched_barrier(0); \
        MFMA_Q(0, 0); \
        RD_B(1, 2, 4); \
        CLOSEBAR; \
        /* P6: Q(0,2); post: a-hi(tB) */ \
        if (NOTLAST_) { STG_A(1, tB + 2, 0, 0); STG_A(1, tB + 2, 1, 0); } \
        __builtin_amdgcn_sched_barrier(0); \
        MFMA_Q(0, 2); \
        RD_A(1, 4); \
        CLOSEBAR; \
        /* P7: Q(4,0) */ \
        if (NOTLAST_) { STG_B(1, tB + 2, 0, 0); STG_B(1, tB + 2, 0, 64); } \
        __builtin_amdgcn_sched_barrier(0); \
        MFMA_Q(4, 0); \
        CLOSEBAR; \
        /* P8: vmcnt certifies tile tA+2; b01+a-lo(tA+2) guarded; Q(4,2) */ \
        if (NOTLAST_) { STG_B(1, tB + 2, 1, 0); STG_B(1, tB + 2, 1, 64); } \
        if (NOTLAST_) { asm volatile("s_waitcnt vmcnt(6)" ::: "memory"); } \
        else         { asm volatile("s_waitcnt vmcnt(0)" ::: "memory"); } \
        __builtin_amdgcn_sched_barrier(0); \
        if (NOTLAST_) { RD_B(0, 0, 2); } \
        MFMA_Q(4, 2); \
        if (NOTLAST_) { RD_A(0, 0); } \
        CLOSEBAR; \
    } while (0)

    for (int j = 0; j < NT / 2 - 1; ++j) { ITER(true); }
    { const int j = NT / 2 - 1; ITER(false); }

#undef ITER
#undef MFMA_Q
#undef CLOSEBAR
#undef RD_A
#undef RD_B
#undef STG_A
#undef STG_B

    // ---- epilogue: LDS-transpose to contiguous row stores (r5-validated) ----
    constexpr int ST = 260;
    float* S = (float*)&L[0][0][0][0][0];
    const int rowq = (lane >> 4) * 4;
    const float* bp = bias + (size_t)e * N;
    const float4 bb4 = *(const float4*)(bp + bn0 + lane * 4);

    unsigned short* Y = (unsigned short*)Cout + (size_t)e * M * N;
    float* O = (float*)Cout + (size_t)e * M * N;

#pragma unroll
    for (int sg = 0; sg < 8; ++sg) {
        __syncthreads();
        if (wr == (sg >> 2)) {
            const int sl = sg & 3;
#pragma unroll
            for (int mm = 0; mm < 2; ++mm) {
#pragma unroll
                for (int n = 0; n < 4; ++n) {
#pragma unroll
                    for (int j2 = 0; j2 < 4; ++j2) {
                        S[(mm * 16 + rowq + j2) * ST + wc * 64 + n * 16 + fr] =
                            acc[2 * sl + mm][n][j2];
                    }
                }
            }
        }
        __syncthreads();
#pragma unroll
        for (int rr = 0; rr < 4; ++rr) {
            const int rl = wid * 4 + rr;
            const int rg = bm0 + sg * 32 + rl;
            f32x4 v = *(const f32x4*)&S[rl * ST + lane * 4];
            v[0] += bb4.x; v[1] += bb4.y; v[2] += bb4.z; v[3] += bb4.w;
            if (OUT_MODE == 0) {
                u16x4 o;
                o[0] = f2bf(fmaxf(v[0], 0.0f));
                o[1] = f2bf(fmaxf(v[1], 0.0f));
                o[2] = f2bf(fmaxf(v[2], 0.0f));
                o[3] = f2bf(fmaxf(v[3], 0.0f));
                *(u16x4*)(Y + (size_t)rg * N + bn0 + lane * 4) = o;
            } else {
                *(f32x4*)(O + (size_t)rg * N + bn0 + lane * 4) = v;
            }
        }
    }
}

extern "C" void kernel_launch(void* const* d_in, const int* in_sizes, int n_in,
                              void* d_out, int out_size, void* d_ws, size_t ws_size,
                              hipStream_t stream) {
    const float* x     = (const float*)d_in[0]; // (E,T,D)
    const float* fc1_w = (const float*)d_in[1]; // (E,D,H)
    const float* fc1_b = (const float*)d_in[2]; // (E,1,H)
    const float* fc2_w = (const float*)d_in[3]; // (E,H,D)
    const float* fc2_b = (const float*)d_in[4]; // (E,1,D)
    float* out = (float*)d_out;

    const size_t n_x  = (size_t)E_ * T_ * D_;
    const size_t n_w1 = (size_t)E_ * D_ * H_;
    const size_t n_w2 = (size_t)E_ * H_ * D_;
    const size_t n_y1 = (size_t)E_ * T_ * H_;

    const size_t need = (n_x + n_w1 + n_w2 + n_y1) * sizeof(unsigned short);
    if (ws_size < need) return;

    unsigned short* xb  = (unsigned short*)d_ws;
    unsigned short* w1t = xb + n_x;    // (E,H,D)
    unsigned short* w2t = w1t + n_w1;  // (E,D,H)
    unsigned short* y1  = w2t + n_w2;  // (E,T,H)

    cvt_x_kernel<<<2048, 256, 0, stream>>>((const float4*)x, (uint2*)xb, (long)(n_x / 4));
    {
        dim3 g(H_ / 64, D_ / 64, E_);
        transpose_cvt_kernel<<<g, 256, 0, stream>>>(fc1_w, w1t, D_, H_);
    }
    {
        dim3 g(D_ / 64, H_ / 64, E_);
        transpose_cvt_kernel<<<g, 256, 0, stream>>>(fc2_w, w2t, H_, D_);
    }
    // GEMM1: y1 = relu(x @ W1 + b1), bf16 out. M=T, N=H, K=D
    {
        dim3 g(H_ / 256, T_ / 256, E_);
        gemm256_kernel<D_, 0><<<g, 512, 0, stream>>>(xb, w1t, fc1_b, (void*)y1, T_, H_);
    }
    // GEMM2: out = y1 @ W2 + b2, f32 out. M=T, N=D, K=H
    {
        dim3 g(D_ / 256, T_ / 256, E_);
        gemm256_kernel<H_, 1><<<g, 512, 0, stream>>>(y1, w2t, fc2_b, (void*)out, T_, D_);
    }
}